// Round 2
// baseline (537.717 us; speedup 1.0000x reference)
//
#include <hip/hip_runtime.h>

// Anchor3DHead fused 1x1-conv heads, R4: un-fission the 2-px/lane kernel.
// R3 post-mortem: launch_bounds(256,8) capped VGPRs at 64 -> compiler fissioned
// the c-loop into two single-pixel passes (VGPR_Count=32, FETCH_SIZE +73%,
// time unchanged). R4 relaxes the cap to (256,6) (~85 VGPR budget) so the
// interleaved 36-accumulator body survives, and adds an explicit chunk-ahead
// float2 prefetch so x-load latency hides under the previous chunk's 72 FMAs.
// Block = 256 threads = 4 waves; block covers 128 pixels (lane -> px 2i,2i+1).
// Wave w owns 18 of 72 output channels over all 384 input channels:
//   w0: cls[0..18)   w1: reg[0..18)   w2: reg[18..36)   w3: reg[36..42)+dir[0..12)
// All 4 waves read the same x columns -> L1/L2 dedupes to one HBM stream.

constexpr int Bn   = 4;
constexpr int Cc   = 384;
constexpr int Hh   = 248;
constexpr int Ww   = 216;
constexpr int HW   = Hh * Ww;          // 53568 (even -> float2 never straddles batch)
constexpr int NPIX = Bn * HW;          // 214272 = 128 * 1674
constexpr int NCLS = 18;
constexpr int NREG = 42;
constexpr int NDIR = 12;
constexpr int CH   = 4;                // channel chunk (x prefetch depth)

// One wave's work: NA outputs from wA (row stride LDA) + NB outputs from wB
// (stride LDB), for TWO pixels per lane. Weight addresses are wave-uniform ->
// scalar loads. x: one coalesced dwordx2 per lane per channel, prefetched one
// chunk ahead so vmcnt waits land after 4x72 FMA cycles, not before them.
template<int NA, int LDA, int NB, int LDB>
__device__ __forceinline__ void cohort_run2(
    const float* __restrict__ xb,
    const float* __restrict__ wA, const float* __restrict__ bA,
    float* __restrict__ oA,
    const float* __restrict__ wB, const float* __restrict__ bB,
    float* __restrict__ oB)
{
    constexpr int NO = NA + NB;
    float a0[NO];   // pixel 2i
    float a1[NO];   // pixel 2i+1
    #pragma unroll
    for (int j = 0; j < NA; ++j) { const float b = bA[j]; a0[j] = b; a1[j] = b; }
    #pragma unroll
    for (int j = 0; j < NB; ++j) { const float b = bB[j]; a0[NA + j] = b; a1[NA + j] = b; }

    // prologue: chunk 0 in flight
    float2 xbuf[CH];
    #pragma unroll
    for (int i = 0; i < CH; ++i)
        xbuf[i] = *reinterpret_cast<const float2*>(xb + (size_t)i * HW);

    for (int c0 = 0; c0 < Cc; c0 += CH) {   // 96 iterations, not unrolled further
        float2 xc[CH];
        #pragma unroll
        for (int i = 0; i < CH; ++i) xc[i] = xbuf[i];

        // issue next chunk's x loads before touching weights/FMAs
        if (c0 + CH < Cc) {
            #pragma unroll
            for (int i = 0; i < CH; ++i)
                xbuf[i] = *reinterpret_cast<const float2*>(xb + (size_t)(c0 + CH + i) * HW);
        }

        #pragma unroll
        for (int i = 0; i < CH; ++i) {
            const float* __restrict__ wra = wA + (size_t)(c0 + i) * LDA;
            const float* __restrict__ wrb = wB + (size_t)(c0 + i) * LDB;
            #pragma unroll
            for (int j = 0; j < NA; ++j) {
                const float wv = wra[j];
                a0[j] = fmaf(xc[i].x, wv, a0[j]);
                a1[j] = fmaf(xc[i].y, wv, a1[j]);
            }
            #pragma unroll
            for (int j = 0; j < NB; ++j) {
                const float wv = wrb[j];
                a0[NA + j] = fmaf(xc[i].x, wv, a0[NA + j]);
                a1[NA + j] = fmaf(xc[i].y, wv, a1[NA + j]);
            }
        }
    }

    #pragma unroll
    for (int j = 0; j < NA; ++j)
        *reinterpret_cast<float2*>(oA + (size_t)j * HW) = make_float2(a0[j], a1[j]);
    #pragma unroll
    for (int j = 0; j < NB; ++j)
        *reinterpret_cast<float2*>(oB + (size_t)j * HW) = make_float2(a0[NA + j], a1[NA + j]);
}

__global__ __launch_bounds__(256, 6) void head_fused_msplit3(
    const float* __restrict__ x,
    const float* __restrict__ wc, const float* __restrict__ bc,
    const float* __restrict__ wr, const float* __restrict__ br,
    const float* __restrict__ wd, const float* __restrict__ bd,
    float* __restrict__ out)
{
    const int w    = threadIdx.x >> 6;        // wave id 0..3 (uniform per wave)
    const int lane = threadIdx.x & 63;
    const int pix  = blockIdx.x * 128 + lane * 2;  // < 214272 exactly
    const int b    = pix / HW;
    const int p    = pix - b * HW;            // even -> 8B-aligned float2

    const float* __restrict__ xb = x + (size_t)b * Cc * HW + p;

    float* __restrict__ outc = out + (size_t)b * NCLS * HW + p;
    float* __restrict__ outr = out + (size_t)Bn * NCLS * HW
                                   + (size_t)b * NREG * HW + p;
    float* __restrict__ outd = out + (size_t)Bn * (NCLS + NREG) * HW
                                   + (size_t)b * NDIR * HW + p;

    if (w == 0) {
        cohort_run2<18, NCLS, 0, 1>(xb, wc, bc, outc, wc, bc, outc);
    } else if (w == 1) {
        cohort_run2<18, NREG, 0, 1>(xb, wr, br, outr, wr, br, outr);
    } else if (w == 2) {
        cohort_run2<18, NREG, 0, 1>(xb, wr + 18, br + 18, outr + (size_t)18 * HW,
                                    wr, br, outr);
    } else {
        cohort_run2<6, NREG, 12, NDIR>(xb, wr + 36, br + 36, outr + (size_t)36 * HW,
                                       wd, bd, outd);
    }
}

extern "C" void kernel_launch(void* const* d_in, const int* in_sizes, int n_in,
                              void* d_out, int out_size, void* d_ws, size_t ws_size,
                              hipStream_t stream) {
    const float* x  = (const float*)d_in[0];
    const float* wc = (const float*)d_in[1];
    const float* bc = (const float*)d_in[2];
    const float* wr = (const float*)d_in[3];
    const float* br = (const float*)d_in[4];
    const float* wd = (const float*)d_in[5];
    const float* bd = (const float*)d_in[6];
    float* out = (float*)d_out;

    dim3 grid(NPIX / 128);   // 1674 blocks, exact cover (128 pixels per block)
    dim3 block(256);
    head_fused_msplit3<<<grid, block, 0, stream>>>(x, wc, bc, wr, br, wd, bd, out);
}